// Round 15
// baseline (189.255 us; speedup 1.0000x reference)
//
#include <hip/hip_runtime.h>
#include <hip/hip_bf16.h>
#include <stdint.h>

#define B_ 2
#define N_ 2048
#define DIM_ 1024
#define HEADS_ 16
#define DH_ 64
#define EPS_ 1e-5f

typedef __attribute__((ext_vector_type(4))) float f32x4;
typedef __attribute__((ext_vector_type(8))) float f32x8;
typedef __attribute__((ext_vector_type(16))) float f32x16;
typedef __attribute__((ext_vector_type(8))) __bf16 bf16x8;
typedef __attribute__((ext_vector_type(4))) unsigned int u32x4;
typedef __attribute__((ext_vector_type(2))) unsigned int u32x2;

__device__ __forceinline__ f32x4 mfma16(bf16x8 a, bf16x8 b, f32x4 c) {
  return __builtin_amdgcn_mfma_f32_16x16x32_bf16(a, b, c, 0, 0, 0);
}

__device__ __forceinline__ f32x16 mfma32(bf16x8 a, bf16x8 b, f32x16 c) {
  return __builtin_amdgcn_mfma_f32_32x32x16_bf16(a, b, c, 0, 0, 0);
}

__device__ __forceinline__ unsigned short f2bf(float x) {
  unsigned int u = __builtin_bit_cast(unsigned int, x);
  u += 0x7fffu + ((u >> 16) & 1u);
  return (unsigned short)(u >> 16);
}

__device__ __forceinline__ unsigned int cvt_pk_bf16(float lo, float hi) {
  unsigned int r;
  asm("v_cvt_pk_bf16_f32 %0, %1, %2" : "=v"(r) : "v"(lo), "v"(hi));
  return r;
}

__device__ __forceinline__ float uasf(unsigned int u) { return __builtin_bit_cast(float, u); }
__device__ __forceinline__ unsigned int fasu(float f) { return __builtin_bit_cast(unsigned int, f); }

__device__ __forceinline__ bf16x8 ld_frag(const unsigned short* p) {
  u32x4 v = *reinterpret_cast<const u32x4*>(p);
  return __builtin_bit_cast(bf16x8, v);
}

__device__ __forceinline__ void gload_lds16(const unsigned short* g, unsigned short* l) {
  __builtin_amdgcn_global_load_lds((const __attribute__((address_space(1))) void*)g,
                                   (__attribute__((address_space(3))) void*)l, 16, 0, 0);
}

// ---------------- LayerNorm over sequence axis ----------------
__global__ __launch_bounds__(256) void ln_part(const float* __restrict__ x,
                                               float* __restrict__ ps,
                                               float* __restrict__ pss) {
  const int d = blockIdx.x * 256 + threadIdx.x;
  const int b = blockIdx.y >> 4, sp = blockIdx.y & 15;
  const float* xp = x + (size_t)(b * N_ + sp * 128) * DIM_ + d;
  float s = 0.f, ss = 0.f;
  for (int i = 0; i < 128; ++i) {
    float v = xp[(size_t)i * DIM_];
    s += v;
    ss += v * v;
  }
  int c = b * DIM_ + d;
  ps[sp * (B_ * DIM_) + c] = s;
  pss[sp * (B_ * DIM_) + c] = ss;
}

__global__ void ln_fin(const float* __restrict__ ps, const float* __restrict__ pss,
                       const float* __restrict__ g, float* __restrict__ meanA,
                       float* __restrict__ sclA) {
  int c = blockIdx.x * 256 + threadIdx.x;
  float s = 0.f, ss = 0.f;
#pragma unroll
  for (int sp = 0; sp < 16; ++sp) {
    s += ps[sp * (B_ * DIM_) + c];
    ss += pss[sp * (B_ * DIM_) + c];
  }
  float m = s * (1.f / N_);
  float v = ss * (1.f / N_) - m * m;
  meanA[c] = m;
  sclA[c] = rsqrtf(fmaxf(v, EPS_)) * g[c & (DIM_ - 1)];
}

__global__ __launch_bounds__(256) void ln_apply(const float* __restrict__ x,
                                                const float* __restrict__ meanA,
                                                const float* __restrict__ sclA,
                                                unsigned short* __restrict__ xn) {
  size_t t = (size_t)blockIdx.x * 256 + threadIdx.x;
  size_t base = t * 8;
  int d0 = (int)(base & (DIM_ - 1));
  int b = base >= (size_t)N_ * DIM_;
  int c = b * DIM_ + d0;
  const float4* xp = reinterpret_cast<const float4*>(x + base);
  const float4* mp = reinterpret_cast<const float4*>(meanA + c);
  const float4* sp = reinterpret_cast<const float4*>(sclA + c);
  float4 x0 = xp[0], x1 = xp[1];
  float4 m0 = mp[0], m1 = mp[1];
  float4 s0 = sp[0], s1 = sp[1];
  union {
    unsigned short u[8];
    u32x4 v;
  } o;
  o.u[0] = f2bf((x0.x - m0.x) * s0.x);
  o.u[1] = f2bf((x0.y - m0.y) * s0.y);
  o.u[2] = f2bf((x0.z - m0.z) * s0.z);
  o.u[3] = f2bf((x0.w - m0.w) * s0.w);
  o.u[4] = f2bf((x1.x - m1.x) * s1.x);
  o.u[5] = f2bf((x1.y - m1.y) * s1.y);
  o.u[6] = f2bf((x1.z - m1.z) * s1.z);
  o.u[7] = f2bf((x1.w - m1.w) * s1.w);
  *reinterpret_cast<u32x4*>(xn + base) = o.v;
}

// ---------------- fp32 -> bf16 weight cast (optional scale) ----------------
__global__ __launch_bounds__(256) void cast_bf16(const float* __restrict__ src,
                                                 unsigned short* __restrict__ dst, float scale) {
  size_t t = (size_t)blockIdx.x * 256 + threadIdx.x;
  size_t base = t * 8;
  const float4* sp = reinterpret_cast<const float4*>(src + base);
  float4 a = sp[0], b4 = sp[1];
  union {
    unsigned short u[8];
    u32x4 v;
  } o;
  o.u[0] = f2bf(a.x * scale);
  o.u[1] = f2bf(a.y * scale);
  o.u[2] = f2bf(a.z * scale);
  o.u[3] = f2bf(a.w * scale);
  o.u[4] = f2bf(b4.x * scale);
  o.u[5] = f2bf(b4.y * scale);
  o.u[6] = f2bf(b4.z * scale);
  o.u[7] = f2bf(b4.w * scale);
  *reinterpret_cast<u32x4*>(dst + base) = o.v;
}

// ---------------- GEMM: C[M,Nc] = A[M,K]bf16 * W[Nc,K]bf16^T ----------------
template <bool OUT_F32>
__global__ __launch_bounds__(256) void gemm_bt(const unsigned short* __restrict__ A,
                                               const unsigned short* __restrict__ W,
                                               void* __restrict__ Cout, int K, int ldc) {
  __shared__ unsigned short sA[128 * 64];
  __shared__ unsigned short sB[128 * 64];
  const int tid = threadIdx.x, lane = tid & 63, w = tid >> 6;
  const int wm = w >> 1, wn = w & 1;
  const int l15 = lane & 15, l4 = lane >> 4;
  const int m0 = blockIdx.y * 128, n0 = blockIdx.x * 128;
  f32x4 acc[4][4] = {};
  for (int kt = 0; kt < K; kt += 64) {
    __syncthreads();
#pragma unroll
    for (int p = 0; p < 4; ++p) {
      int flat = p * 256 + tid;
      int row = flat >> 3, c = flat & 7;
      int cs = c ^ (row & 7);
      gload_lds16(A + (size_t)(m0 + row) * K + kt + cs * 8, sA + (size_t)(p * 256 + w * 64) * 8);
      gload_lds16(W + (size_t)(n0 + row) * K + kt + cs * 8, sB + (size_t)(p * 256 + w * 64) * 8);
    }
    __syncthreads();
#pragma unroll
    for (int kk = 0; kk < 2; ++kk) {
      bf16x8 af[4], bfr[4];
#pragma unroll
      for (int i = 0; i < 4; ++i) {
        int rowA = wm * 64 + i * 16 + l15;
        af[i] = ld_frag(sA + rowA * 64 + (((kk * 4 + l4) ^ (rowA & 7)) * 8));
        int rowB = wn * 64 + i * 16 + l15;
        bfr[i] = ld_frag(sB + rowB * 64 + (((kk * 4 + l4) ^ (rowB & 7)) * 8));
      }
#pragma unroll
      for (int i = 0; i < 4; ++i)
#pragma unroll
        for (int j = 0; j < 4; ++j) acc[i][j] = mfma16(af[i], bfr[j], acc[i][j]);
    }
  }
#pragma unroll
  for (int i = 0; i < 4; ++i)
#pragma unroll
    for (int j = 0; j < 4; ++j)
#pragma unroll
      for (int r = 0; r < 4; ++r) {
        size_t off =
            (size_t)(m0 + wm * 64 + i * 16 + l4 * 4 + r) * ldc + (n0 + wn * 64 + j * 16 + l15);
        if (OUT_F32)
          ((float*)Cout)[off] = acc[i][j][r];
        else
          ((unsigned short*)Cout)[off] = f2bf(acc[i][j][r]);
      }
}

// ---------------- V transpose: qkv v-block -> Vt[b][h][dh][n] ----------------
__global__ __launch_bounds__(256) void transpose_v(const unsigned short* __restrict__ qkv,
                                                   unsigned short* __restrict__ Vt) {
  __shared__ unsigned short tt[64][65];
  const int tid = threadIdx.x;
  const int h = blockIdx.y >> 1, b = blockIdx.y & 1;
  const int n0 = blockIdx.x * 64;
  const unsigned short* src = qkv + (size_t)(b * N_ + n0) * 3072 + 2048 + h * 64;
#pragma unroll
  for (int i = 0; i < 16; ++i) {
    int idx = i * 256 + tid;
    int r = idx >> 6, c = idx & 63;
    tt[r][c] = src[(size_t)r * 3072 + c];
  }
  __syncthreads();
  unsigned short* dst = Vt + (size_t)(b * HEADS_ + h) * 64 * N_ + n0;
#pragma unroll
  for (int i = 0; i < 16; ++i) {
    int idx = i * 256 + tid;
    int dh = idx >> 6, nn = idx & 63;
    dst[(size_t)dh * N_ + nn] = tt[nn][dh];
  }
}

// ---------------- Flash attention: depth-2 bias pipeline, counted vmcnt -----
// r13/r14 failed with IDENTICAL absmax (deterministic bug, not a race): the
// LDBIAS refactor dropped the per-row base "+ l31*64" that r10/r12's passing
// macro had -- every lane read q-row 0's bias slice. Restored here (one line).
// Sched_barrier pins kept: they enforce the vmem issue order
// [bias[j](8), KV[j](2), bias[j+1](8)] that makes vmcnt(8) drain exactly
// bias[j]+KV[j] while bias[j+1] rides through the barrier (T4).
__global__ __launch_bounds__(512, 2) void flash_attn(const unsigned short* __restrict__ qkv,
                                                     const float* __restrict__ bias,
                                                     const unsigned short* __restrict__ Vt,
                                                     unsigned short* __restrict__ Oatt) {
  __shared__ unsigned short sK[2][64 * 64];  // 16 KB (row=key, 64 dh)
  __shared__ unsigned short sV[2][64 * 64];  // 16 KB (row=d, 64 keys)
  __shared__ float sBias[8][2][32 * 64];     // 128 KB (per-wave 32q x 64k)

  const int tid = threadIdx.x, lane = tid & 63, w = tid >> 6;  // w 0..7
  const int l31 = lane & 31, hi = lane >> 5;
  const int r = blockIdx.x;
  const int bh = r & 31, iblk = r >> 5;
  const int h = bh & 15, b = bh >> 4;
  const int qwb = iblk * 256 + w * 32;  // wave's q base

  const unsigned short* Kg = qkv + (size_t)b * N_ * 3072 + 1024 + h * 64;
  const unsigned short* VtB = Vt + (size_t)(b * HEADS_ + h) * 64 * N_;
  const float* bias_h = bias + (size_t)h * N_ * N_;

  // K/V staging: 1 gload each per wave per tile (wave w -> rows w*8..w*8+7)
  const int krow = w * 8 + (lane >> 3);
  const int kcs = (lane & 7) ^ (krow & 7);
  const unsigned short* kSrc = Kg + (size_t)krow * 3072 + kcs * 8;
  const unsigned short* vSrc = VtB + (size_t)krow * N_ + kcs * 8;

#define STAGE_KV(S, JN)                                      \
  gload_lds16(kSrc + (size_t)(JN) * 3072, sK[S] + w * 512);  \
  gload_lds16(vSrc + (JN), sV[S] + w * 512);

  // Bias staging: 8 gloads/wave/tile; instr i covers rows 4i..4i+3 (16 chunks
  // of 16B per 256B row); slot s of row r holds global chunk s ^ (r & 15).
  const int ln4b = lane >> 4, l15b = lane & 15;
  const float* bp0 =
      bias_h + (size_t)(qwb + 0 + ln4b) * N_ + ((l15b ^ ((0 + ln4b) & 15)) << 2);
  const float* bp1 =
      bias_h + (size_t)(qwb + 4 + ln4b) * N_ + ((l15b ^ ((4 + ln4b) & 15)) << 2);
  const float* bp2 =
      bias_h + (size_t)(qwb + 8 + ln4b) * N_ + ((l15b ^ ((8 + ln4b) & 15)) << 2);
  const float* bp3 =
      bias_h + (size_t)(qwb + 12 + ln4b) * N_ + ((l15b ^ ((12 + ln4b) & 15)) << 2);

#define STAGE_BIAS(DSTUS, JN)                                                  \
  gload_lds16((const unsigned short*)(bp0 + (JN)), (DSTUS) + 0 * 512);         \
  gload_lds16((const unsigned short*)(bp1 + (JN)), (DSTUS) + 1 * 512);         \
  gload_lds16((const unsigned short*)(bp2 + (JN)), (DSTUS) + 2 * 512);         \
  gload_lds16((const unsigned short*)(bp3 + (JN)), (DSTUS) + 3 * 512);         \
  gload_lds16((const unsigned short*)(bp0 + 16 * N_ + (JN)), (DSTUS) + 4 * 512); \
  gload_lds16((const unsigned short*)(bp1 + 16 * N_ + (JN)), (DSTUS) + 5 * 512); \
  gload_lds16((const unsigned short*)(bp2 + 16 * N_ + (JN)), (DSTUS) + 6 * 512); \
  gload_lds16((const unsigned short*)(bp3 + 16 * N_ + (JN)), (DSTUS) + 7 * 512);

// C-block from LDS bias: C[rr] = bias[q=l31][CHB*4 + 8*(rr>>2)+4*hi+(rr&3)]
// ROW BASE l31*64 restored (r13/r14 bug: read row 0 for all lanes).
#define LDBIAS(DST, MYB, CHB)                                                  \
  {                                                                            \
    const float* myB_ = (MYB) + (size_t)l31 * 64;                              \
    f32x4 t0 = *reinterpret_cast<const f32x4*>(myB_ + ((((CHB) + 0 + hi) ^ (l31 & 15)) << 2)); \
    f32x4 t1 = *reinterpret_cast<const f32x4*>(myB_ + ((((CHB) + 2 + hi) ^ (l31 & 15)) << 2)); \
    f32x4 t2 = *reinterpret_cast<const f32x4*>(myB_ + ((((CHB) + 4 + hi) ^ (l31 & 15)) << 2)); \
    f32x4 t3 = *reinterpret_cast<const f32x4*>(myB_ + ((((CHB) + 6 + hi) ^ (l31 & 15)) << 2)); \
    f32x8 u0_ = __builtin_shufflevector(t0, t1, 0, 1, 2, 3, 4, 5, 6, 7);       \
    f32x8 u1_ = __builtin_shufflevector(t2, t3, 0, 1, 2, 3, 4, 5, 6, 7);       \
    DST = __builtin_shufflevector(u0_, u1_, 0, 1, 2, 3, 4, 5, 6, 7, 8, 9, 10,  \
                                  11, 12, 13, 14, 15);                         \
  }

#define FRAGK(OUT, SRC, ROWB, CH)                                       \
  {                                                                     \
    int row_ = (ROWB) + l31;                                            \
    OUT = ld_frag((SRC) + row_ * 64 + (((CH) ^ (row_ & 7)) * 8));       \
  }

// pack one 32-key S block into two PV B-frags (verified r9/r10/r12)
#define PACK2(S, PLO, PHI)                                                 \
  {                                                                        \
    unsigned int w0 = cvt_pk_bf16(S[0], S[1]), w1 = cvt_pk_bf16(S[2], S[3]);     \
    unsigned int w2 = cvt_pk_bf16(S[4], S[5]), w3 = cvt_pk_bf16(S[6], S[7]);     \
    unsigned int w4 = cvt_pk_bf16(S[8], S[9]), w5 = cvt_pk_bf16(S[10], S[11]);   \
    unsigned int w6 = cvt_pk_bf16(S[12], S[13]), w7 = cvt_pk_bf16(S[14], S[15]); \
    auto rA = __builtin_amdgcn_permlane32_swap(w0, w2, false, false);      \
    auto rB = __builtin_amdgcn_permlane32_swap(w1, w3, false, false);      \
    auto rC = __builtin_amdgcn_permlane32_swap(w4, w6, false, false);      \
    auto rD = __builtin_amdgcn_permlane32_swap(w5, w7, false, false);      \
    u32x4 pw;                                                              \
    pw[0] = rA[0]; pw[1] = rB[0]; pw[2] = rA[1]; pw[3] = rB[1];            \
    PLO = __builtin_bit_cast(bf16x8, pw);                                  \
    pw[0] = rC[0]; pw[1] = rD[0]; pw[2] = rC[1]; pw[3] = rD[1];            \
    PHI = __builtin_bit_cast(bf16x8, pw);                                  \
  }

  // Q B-frags: qfK covers d = K*16 + hi*8 .. +7 for q = qwb + l31
  bf16x8 qf0, qf1, qf2, qf3;
  {
    const unsigned short* Qg =
        qkv + (size_t)(b * N_ + qwb + l31) * 3072 + h * 64 + hi * 8;
    qf0 = ld_frag(Qg);
    qf1 = ld_frag(Qg + 16);
    qf2 = ld_frag(Qg + 32);
    qf3 = ld_frag(Qg + 48);
  }

  f32x16 o0 = {}, o1 = {};
  float m_run = -1e30f, l_run = 0.f;

  // prologue — queue order IS the correctness invariant; pin each group.
  STAGE_BIAS(reinterpret_cast<unsigned short*>(&sBias[w][0][0]), 0)
  __builtin_amdgcn_sched_barrier(0);
  STAGE_KV(0, 0)
  __builtin_amdgcn_sched_barrier(0);
  STAGE_BIAS(reinterpret_cast<unsigned short*>(&sBias[w][1][0]), 64)
  __builtin_amdgcn_sched_barrier(0);

  const int NT = N_ / 64;  // 32
  for (int j = 0; j < NT; ++j) {
    // a. counted drain: bias[j] + KV[j]; bias[j+1] (newest 8) stays in flight
    if (j == NT - 1)
      asm volatile("s_waitcnt vmcnt(0)" ::: "memory");
    else
      asm volatile("s_waitcnt vmcnt(8)" ::: "memory");
    __builtin_amdgcn_s_barrier();
    const int slot = j & 1;
    const unsigned short* sKc = sK[slot];
    const unsigned short* sVc = sV[slot];
    float* sBw = &sBias[w][slot][0];

    // b. KV prefetch j+1 -> other slot (cover = rest of this iteration)
    if (j + 1 < NT) {
      STAGE_KV(slot ^ 1, (size_t)(j + 1) * 64)
      __builtin_amdgcn_sched_barrier(0);  // pin: KV[j+1] older than bias[j+2]
    }

    // c. bias regs for tile j (C-operands)
    f32x16 SA0, SA1;
    LDBIAS(SA0, sBw, 0)
    LDBIAS(SA1, sBw, 8)
    asm volatile("s_waitcnt lgkmcnt(0)" ::: "memory");
    __builtin_amdgcn_sched_barrier(0);  // regs live before slot overwrite

    // d. bias prefetch j+2 -> same (just-consumed) slot
    if (j + 2 < NT) {
      STAGE_BIAS(reinterpret_cast<unsigned short*>(sBw), (size_t)(j + 2) * 64)
      __builtin_amdgcn_sched_barrier(0);  // pin group before compute
    }

    // e. S^T = K Q^T + bias
    __builtin_amdgcn_s_setprio(1);
    {
      bf16x8 kf;
      FRAGK(kf, sKc, 0, 0 + hi)  SA0 = mfma32(kf, qf0, SA0);
      FRAGK(kf, sKc, 0, 2 + hi)  SA0 = mfma32(kf, qf1, SA0);
      FRAGK(kf, sKc, 0, 4 + hi)  SA0 = mfma32(kf, qf2, SA0);
      FRAGK(kf, sKc, 0, 6 + hi)  SA0 = mfma32(kf, qf3, SA0);
      FRAGK(kf, sKc, 32, 0 + hi) SA1 = mfma32(kf, qf0, SA1);
      FRAGK(kf, sKc, 32, 2 + hi) SA1 = mfma32(kf, qf1, SA1);
      FRAGK(kf, sKc, 32, 4 + hi) SA1 = mfma32(kf, qf2, SA1);
      FRAGK(kf, sKc, 32, 6 + hi) SA1 = mfma32(kf, qf3, SA1);
    }
    __builtin_amdgcn_s_setprio(0);

    // online softmax over 64 keys (2 parallel chains + 1 permlane reduce)
    float c0 = SA0[0], c1 = SA1[0];
#pragma unroll
    for (int i = 1; i < 16; ++i) {
      c0 = fmaxf(c0, SA0[i]);
      c1 = fmaxf(c1, SA1[i]);
    }
    float mx = fmaxf(c0, c1);
    {
      auto pr_ = __builtin_amdgcn_permlane32_swap(fasu(mx), fasu(mx), false, false);
      mx = fmaxf(uasf(pr_[0]), uasf(pr_[1]));
    }
    float mn = fmaxf(m_run, mx);
    float alpha = __expf(m_run - mn);
#pragma unroll
    for (int i = 0; i < 16; ++i) {
      SA0[i] = __expf(SA0[i] - mn);
      SA1[i] = __expf(SA1[i] - mn);
    }
    float r0 = 0.f, r1 = 0.f;
#pragma unroll
    for (int i = 0; i < 16; ++i) {
      r0 += SA0[i];
      r1 += SA1[i];
    }
    float rs = r0 + r1;
    {
      auto pr_ = __builtin_amdgcn_permlane32_swap(fasu(rs), fasu(rs), false, false);
      rs = uasf(pr_[0]) + uasf(pr_[1]);
    }
    l_run = l_run * alpha + rs;
    m_run = mn;
#pragma unroll
    for (int i = 0; i < 16; ++i) {
      o0[i] *= alpha;
      o1[i] *= alpha;
    }

    // P -> PV B-frags in-register
    bf16x8 pA0, pA1, pA2, pA3;
    PACK2(SA0, pA0, pA1)
    PACK2(SA1, pA2, pA3)

    // O^T += V^T P^T
    __builtin_amdgcn_s_setprio(1);
    {
      bf16x8 vf;
      FRAGK(vf, sVc, 0, 0 + hi)  o0 = mfma32(vf, pA0, o0);
      FRAGK(vf, sVc, 0, 2 + hi)  o0 = mfma32(vf, pA1, o0);
      FRAGK(vf, sVc, 0, 4 + hi)  o0 = mfma32(vf, pA2, o0);
      FRAGK(vf, sVc, 0, 6 + hi)  o0 = mfma32(vf, pA3, o0);
      FRAGK(vf, sVc, 32, 0 + hi) o1 = mfma32(vf, pA0, o1);
      FRAGK(vf, sVc, 32, 2 + hi) o1 = mfma32(vf, pA1, o1);
      FRAGK(vf, sVc, 32, 4 + hi) o1 = mfma32(vf, pA2, o1);
      FRAGK(vf, sVc, 32, 6 + hi) o1 = mfma32(vf, pA3, o1);
    }
    __builtin_amdgcn_s_setprio(0);
  }
#undef STAGE_KV
#undef STAGE_BIAS
#undef LDBIAS
#undef FRAGK
#undef PACK2

  // epilogue: O[q][d] = O^T / l
  float inv = 1.f / l_run;
  unsigned short* orow =
      Oatt + (size_t)(b * N_ + qwb + l31) * 1024 + h * 64 + hi * 4;
#pragma unroll
  for (int g = 0; g < 4; ++g) {
    u32x2 pk0;
    pk0[0] = cvt_pk_bf16(o0[g * 4 + 0] * inv, o0[g * 4 + 1] * inv);
    pk0[1] = cvt_pk_bf16(o0[g * 4 + 2] * inv, o0[g * 4 + 3] * inv);
    *reinterpret_cast<u32x2*>(orow + g * 8) = pk0;
    u32x2 pk1;
    pk1[0] = cvt_pk_bf16(o1[g * 4 + 0] * inv, o1[g * 4 + 1] * inv);
    pk1[1] = cvt_pk_bf16(o1[g * 4 + 2] * inv, o1[g * 4 + 3] * inv);
    *reinterpret_cast<u32x2*>(orow + 32 + g * 8) = pk1;
  }
}

extern "C" void kernel_launch(void* const* d_in, const int* in_sizes, int n_in, void* d_out,
                              int out_size, void* d_ws, size_t ws_size, hipStream_t stream) {
  const float* x = (const float*)d_in[0];
  const float* bias = (const float*)d_in[1];
  const float* g = (const float*)d_in[2];
  const float* wq = (const float*)d_in[3];
  const float* wkv = (const float*)d_in[4];
  const float* wout = (const float*)d_in[5];
  float* out = (float*)d_out;

  float* ps = (float*)d_ws;
  float* pss = ps + 16 * B_ * DIM_;
  float* meanA = pss + 16 * B_ * DIM_;
  float* sclA = meanA + B_ * DIM_;
  unsigned short* xn = (unsigned short*)(sclA + B_ * DIM_);
  unsigned short* Wqkv = xn + (size_t)4096 * 1024;
  unsigned short* WoutB = Wqkv + (size_t)3072 * 1024;
  unsigned short* qkvb = WoutB + (size_t)1024 * 1024;
  unsigned short* Vt = qkvb + (size_t)4096 * 3072;
  unsigned short* Oatt = xn;  // alias: xn dead after QKV GEMM

  ln_part<<<dim3(DIM_ / 256, B_ * 16), 256, 0, stream>>>(x, ps, pss);
  ln_fin<<<dim3((B_ * DIM_) / 256), 256, 0, stream>>>(ps, pss, g, meanA, sclA);
  ln_apply<<<dim3((B_ * N_ * DIM_) / 2048), 256, 0, stream>>>(x, meanA, sclA, xn);
  cast_bf16<<<dim3((DIM_ * DIM_) / 2048), 256, 0, stream>>>(wq, Wqkv, 0.125f);
  cast_bf16<<<dim3((2 * DIM_ * DIM_) / 2048), 256, 0, stream>>>(wkv, Wqkv + (size_t)DIM_ * DIM_,
                                                                1.0f);
  cast_bf16<<<dim3((DIM_ * DIM_) / 2048), 256, 0, stream>>>(wout, WoutB, 1.0f);
  gemm_bt<false><<<dim3(3072 / 128, 4096 / 128), 256, 0, stream>>>(xn, Wqkv, qkvb, DIM_, 3072);
  transpose_v<<<dim3(N_ / 64, B_ * HEADS_), 256, 0, stream>>>(qkvb, Vt);
  flash_attn<<<dim3(256), 512, 0, stream>>>(qkvb, bias, Vt, Oatt);
  gemm_bt<true><<<dim3(1024 / 128, 4096 / 128), 256, 0, stream>>>(Oatt, WoutB, out, DIM_, 1024);
}

// Round 16
// 174.404 us; speedup vs baseline: 1.0852x; 1.0852x over previous
//
#include <hip/hip_runtime.h>
#include <hip/hip_bf16.h>
#include <stdint.h>

#define B_ 2
#define N_ 2048
#define DIM_ 1024
#define HEADS_ 16
#define DH_ 64
#define EPS_ 1e-5f

typedef __attribute__((ext_vector_type(4))) float f32x4;
typedef __attribute__((ext_vector_type(8))) float f32x8;
typedef __attribute__((ext_vector_type(16))) float f32x16;
typedef __attribute__((ext_vector_type(8))) __bf16 bf16x8;
typedef __attribute__((ext_vector_type(4))) unsigned int u32x4;
typedef __attribute__((ext_vector_type(2))) unsigned int u32x2;

__device__ __forceinline__ f32x4 mfma16(bf16x8 a, bf16x8 b, f32x4 c) {
  return __builtin_amdgcn_mfma_f32_16x16x32_bf16(a, b, c, 0, 0, 0);
}

__device__ __forceinline__ f32x16 mfma32(bf16x8 a, bf16x8 b, f32x16 c) {
  return __builtin_amdgcn_mfma_f32_32x32x16_bf16(a, b, c, 0, 0, 0);
}

__device__ __forceinline__ unsigned short f2bf(float x) {
  unsigned int u = __builtin_bit_cast(unsigned int, x);
  u += 0x7fffu + ((u >> 16) & 1u);
  return (unsigned short)(u >> 16);
}

__device__ __forceinline__ unsigned int cvt_pk_bf16(float lo, float hi) {
  unsigned int r;
  asm("v_cvt_pk_bf16_f32 %0, %1, %2" : "=v"(r) : "v"(lo), "v"(hi));
  return r;
}

__device__ __forceinline__ float uasf(unsigned int u) { return __builtin_bit_cast(float, u); }
__device__ __forceinline__ unsigned int fasu(float f) { return __builtin_bit_cast(unsigned int, f); }

__device__ __forceinline__ bf16x8 ld_frag(const unsigned short* p) {
  u32x4 v = *reinterpret_cast<const u32x4*>(p);
  return __builtin_bit_cast(bf16x8, v);
}

__device__ __forceinline__ void gload_lds16(const unsigned short* g, unsigned short* l) {
  __builtin_amdgcn_global_load_lds((const __attribute__((address_space(1))) void*)g,
                                   (__attribute__((address_space(3))) void*)l, 16, 0, 0);
}

// ---------------- LayerNorm over sequence axis ----------------
__global__ __launch_bounds__(256) void ln_part(const float* __restrict__ x,
                                               float* __restrict__ ps,
                                               float* __restrict__ pss) {
  const int d = blockIdx.x * 256 + threadIdx.x;
  const int b = blockIdx.y >> 4, sp = blockIdx.y & 15;
  const float* xp = x + (size_t)(b * N_ + sp * 128) * DIM_ + d;
  float s = 0.f, ss = 0.f;
  for (int i = 0; i < 128; ++i) {
    float v = xp[(size_t)i * DIM_];
    s += v;
    ss += v * v;
  }
  int c = b * DIM_ + d;
  ps[sp * (B_ * DIM_) + c] = s;
  pss[sp * (B_ * DIM_) + c] = ss;
}

__global__ void ln_fin(const float* __restrict__ ps, const float* __restrict__ pss,
                       const float* __restrict__ g, float* __restrict__ meanA,
                       float* __restrict__ sclA) {
  int c = blockIdx.x * 256 + threadIdx.x;
  float s = 0.f, ss = 0.f;
#pragma unroll
  for (int sp = 0; sp < 16; ++sp) {
    s += ps[sp * (B_ * DIM_) + c];
    ss += pss[sp * (B_ * DIM_) + c];
  }
  float m = s * (1.f / N_);
  float v = ss * (1.f / N_) - m * m;
  meanA[c] = m;
  sclA[c] = rsqrtf(fmaxf(v, EPS_)) * g[c & (DIM_ - 1)];
}

__global__ __launch_bounds__(256) void ln_apply(const float* __restrict__ x,
                                                const float* __restrict__ meanA,
                                                const float* __restrict__ sclA,
                                                unsigned short* __restrict__ xn) {
  size_t t = (size_t)blockIdx.x * 256 + threadIdx.x;
  size_t base = t * 8;
  int d0 = (int)(base & (DIM_ - 1));
  int b = base >= (size_t)N_ * DIM_;
  int c = b * DIM_ + d0;
  const float4* xp = reinterpret_cast<const float4*>(x + base);
  const float4* mp = reinterpret_cast<const float4*>(meanA + c);
  const float4* sp = reinterpret_cast<const float4*>(sclA + c);
  float4 x0 = xp[0], x1 = xp[1];
  float4 m0 = mp[0], m1 = mp[1];
  float4 s0 = sp[0], s1 = sp[1];
  union {
    unsigned short u[8];
    u32x4 v;
  } o;
  o.u[0] = f2bf((x0.x - m0.x) * s0.x);
  o.u[1] = f2bf((x0.y - m0.y) * s0.y);
  o.u[2] = f2bf((x0.z - m0.z) * s0.z);
  o.u[3] = f2bf((x0.w - m0.w) * s0.w);
  o.u[4] = f2bf((x1.x - m1.x) * s1.x);
  o.u[5] = f2bf((x1.y - m1.y) * s1.y);
  o.u[6] = f2bf((x1.z - m1.z) * s1.z);
  o.u[7] = f2bf((x1.w - m1.w) * s1.w);
  *reinterpret_cast<u32x4*>(xn + base) = o.v;
}

// ---------------- fp32 -> bf16 weight cast (optional scale) ----------------
__global__ __launch_bounds__(256) void cast_bf16(const float* __restrict__ src,
                                                 unsigned short* __restrict__ dst, float scale) {
  size_t t = (size_t)blockIdx.x * 256 + threadIdx.x;
  size_t base = t * 8;
  const float4* sp = reinterpret_cast<const float4*>(src + base);
  float4 a = sp[0], b4 = sp[1];
  union {
    unsigned short u[8];
    u32x4 v;
  } o;
  o.u[0] = f2bf(a.x * scale);
  o.u[1] = f2bf(a.y * scale);
  o.u[2] = f2bf(a.z * scale);
  o.u[3] = f2bf(a.w * scale);
  o.u[4] = f2bf(b4.x * scale);
  o.u[5] = f2bf(b4.y * scale);
  o.u[6] = f2bf(b4.z * scale);
  o.u[7] = f2bf(b4.w * scale);
  *reinterpret_cast<u32x4*>(dst + base) = o.v;
}

// ---------------- GEMM: C[M,Nc] = A[M,K]bf16 * W[Nc,K]bf16^T ----------------
template <bool OUT_F32>
__global__ __launch_bounds__(256) void gemm_bt(const unsigned short* __restrict__ A,
                                               const unsigned short* __restrict__ W,
                                               void* __restrict__ Cout, int K, int ldc) {
  __shared__ unsigned short sA[128 * 64];
  __shared__ unsigned short sB[128 * 64];
  const int tid = threadIdx.x, lane = tid & 63, w = tid >> 6;
  const int wm = w >> 1, wn = w & 1;
  const int l15 = lane & 15, l4 = lane >> 4;
  const int m0 = blockIdx.y * 128, n0 = blockIdx.x * 128;
  f32x4 acc[4][4] = {};
  for (int kt = 0; kt < K; kt += 64) {
    __syncthreads();
#pragma unroll
    for (int p = 0; p < 4; ++p) {
      int flat = p * 256 + tid;
      int row = flat >> 3, c = flat & 7;
      int cs = c ^ (row & 7);
      gload_lds16(A + (size_t)(m0 + row) * K + kt + cs * 8, sA + (size_t)(p * 256 + w * 64) * 8);
      gload_lds16(W + (size_t)(n0 + row) * K + kt + cs * 8, sB + (size_t)(p * 256 + w * 64) * 8);
    }
    __syncthreads();
#pragma unroll
    for (int kk = 0; kk < 2; ++kk) {
      bf16x8 af[4], bfr[4];
#pragma unroll
      for (int i = 0; i < 4; ++i) {
        int rowA = wm * 64 + i * 16 + l15;
        af[i] = ld_frag(sA + rowA * 64 + (((kk * 4 + l4) ^ (rowA & 7)) * 8));
        int rowB = wn * 64 + i * 16 + l15;
        bfr[i] = ld_frag(sB + rowB * 64 + (((kk * 4 + l4) ^ (rowB & 7)) * 8));
      }
#pragma unroll
      for (int i = 0; i < 4; ++i)
#pragma unroll
        for (int j = 0; j < 4; ++j) acc[i][j] = mfma16(af[i], bfr[j], acc[i][j]);
    }
  }
#pragma unroll
  for (int i = 0; i < 4; ++i)
#pragma unroll
    for (int j = 0; j < 4; ++j)
#pragma unroll
      for (int r = 0; r < 4; ++r) {
        size_t off =
            (size_t)(m0 + wm * 64 + i * 16 + l4 * 4 + r) * ldc + (n0 + wn * 64 + j * 16 + l15);
        if (OUT_F32)
          ((float*)Cout)[off] = acc[i][j][r];
        else
          ((unsigned short*)Cout)[off] = f2bf(acc[i][j][r]);
      }
}

// ---------------- V transpose: qkv v-block -> Vt[b][h][dh][n] ----------------
__global__ __launch_bounds__(256) void transpose_v(const unsigned short* __restrict__ qkv,
                                                   unsigned short* __restrict__ Vt) {
  __shared__ unsigned short tt[64][65];
  const int tid = threadIdx.x;
  const int h = blockIdx.y >> 1, b = blockIdx.y & 1;
  const int n0 = blockIdx.x * 64;
  const unsigned short* src = qkv + (size_t)(b * N_ + n0) * 3072 + 2048 + h * 64;
#pragma unroll
  for (int i = 0; i < 16; ++i) {
    int idx = i * 256 + tid;
    int r = idx >> 6, c = idx & 63;
    tt[r][c] = src[(size_t)r * 3072 + c];
  }
  __syncthreads();
  unsigned short* dst = Vt + (size_t)(b * HEADS_ + h) * 64 * N_ + n0;
#pragma unroll
  for (int i = 0; i < 16; ++i) {
    int idx = i * 256 + tid;
    int dh = idx >> 6, nn = idx & 63;
    dst[(size_t)dh * N_ + nn] = tt[nn][dh];
  }
}

// ---------------- Flash attention: batch-fused pairs ------------------------
// r12 pair structure, but each block covers one (h, iblk=128q) with BOTH
// batches: 8 waves = 4 q-sub-blocks x 2 b; wave pair (w, w+4) shares one bias
// slice (bias has no batch dim) -> bias global requests halve BY CONSTRUCTION
// (268 MB unique, no L2-dedup reliance), bias LDS writes halve. K/V staged
// for both b (qkv/Vt are L3-resident, extra requests are cheap). LDS 128 KB.
// One extra mid-iteration barrier closes the pair-share overwrite race.
__global__ __launch_bounds__(512, 2) void flash_attn(const unsigned short* __restrict__ qkv,
                                                     const float* __restrict__ bias,
                                                     const unsigned short* __restrict__ Vt,
                                                     unsigned short* __restrict__ Oatt) {
  __shared__ unsigned short sK[2 * 128 * 64];  // 32 KB: [b][key-pair rows][64 dh]
  __shared__ unsigned short sV[2 * 64 * 128];  // 32 KB: [b][d rows][128 keys]
  __shared__ float sBias[4][32 * 128];         // 64 KB: per-slice 32q x 128k

  const int tid = threadIdx.x, lane = tid & 63, w = tid >> 6;  // w 0..7
  const int l31 = lane & 31, hi = lane >> 5;
  const int id = blockIdx.x;
  const int h = id & 15, iblk = id >> 4;  // id%8=h%8: all iblk of a head share an XCD
  const int sl = w & 3, wb = w >> 2;      // q-sub-block / batch of this wave
  const int qwb = iblk * 128 + sl * 32;

  const unsigned short* Kg0 = qkv + 1024 + h * 64;
  const unsigned short* Kg1 = Kg0 + (size_t)N_ * 3072;
  const unsigned short* Vt0 = Vt + (size_t)h * 64 * N_;
  const unsigned short* Vt1 = Vt0 + (size_t)HEADS_ * 64 * N_;
  const float* bias_h = bias + (size_t)h * N_ * N_;

  // K staging: 4 gloads/thread; flat chunk kflat = q*512+tid ->
  // b = q>>1, row = (q&1)*64 + tid>>3, chunk = tid&7 (slot c holds global c^(row&7))
  const int krow_t = tid >> 3, kcs_t = (tid & 7) ^ (krow_t & 7);
  const unsigned short* kS0 = Kg0 + (size_t)krow_t * 3072 + kcs_t * 8;
  const unsigned short* kS1 = kS0 + (size_t)64 * 3072;
  const unsigned short* kS2 = Kg1 + (size_t)krow_t * 3072 + kcs_t * 8;
  const unsigned short* kS3 = kS2 + (size_t)64 * 3072;
  unsigned short* kD0 = sK + (size_t)(0 * 512 + w * 64) * 8;
  unsigned short* kD1 = sK + (size_t)(1 * 512 + w * 64) * 8;
  unsigned short* kD2 = sK + (size_t)(2 * 512 + w * 64) * 8;
  unsigned short* kD3 = sK + (size_t)(3 * 512 + w * 64) * 8;

  // V staging: 4 gloads/thread; b = q>>1, row = (q&1)*32 + tid>>4, chunk tid&15
  const int vrow_t = tid >> 4, vcs_t = (tid & 15) ^ (vrow_t & 15);
  const unsigned short* vS0 = Vt0 + (size_t)vrow_t * N_ + vcs_t * 8;
  const unsigned short* vS1 = vS0 + (size_t)32 * N_;
  const unsigned short* vS2 = Vt1 + (size_t)vrow_t * N_ + vcs_t * 8;
  const unsigned short* vS3 = vS2 + (size_t)32 * N_;
  unsigned short* vD0 = sV + (size_t)(0 * 512 + w * 64) * 8;
  unsigned short* vD1 = sV + (size_t)(1 * 512 + w * 64) * 8;
  unsigned short* vD2 = sV + (size_t)(2 * 512 + w * 64) * 8;
  unsigned short* vD3 = sV + (size_t)(3 * 512 + w * 64) * 8;

#define STAGE_KV(JN)                                  \
  gload_lds16(kS0 + (size_t)(JN) * 3072, kD0);        \
  gload_lds16(kS1 + (size_t)(JN) * 3072, kD1);        \
  gload_lds16(kS2 + (size_t)(JN) * 3072, kD2);        \
  gload_lds16(kS3 + (size_t)(JN) * 3072, kD3);        \
  gload_lds16(vS0 + (JN), vD0);                       \
  gload_lds16(vS1 + (JN), vD1);                       \
  gload_lds16(vS2 + (JN), vD2);                       \
  gload_lds16(vS3 + (JN), vD3);

  // Bias staging: wave w stages rows 16*wb + {2i+brr} (i=0..7) of slice sl.
  // Slot s of row r holds global chunk s ^ r (r = q-local row, 0..31).
  const int brr = lane >> 5, bsl = lane & 31;
  const int rl0 = 16 * wb + 0 + brr, rl1 = 16 * wb + 2 + brr;
  const int rl2 = 16 * wb + 4 + brr, rl3 = 16 * wb + 6 + brr;
  const int rl4 = 16 * wb + 8 + brr, rl5 = 16 * wb + 10 + brr;
  const int rl6 = 16 * wb + 12 + brr, rl7 = 16 * wb + 14 + brr;
  const float* bq0 = bias_h + (size_t)(qwb + rl0) * N_ + ((bsl ^ rl0) << 2);
  const float* bq1 = bias_h + (size_t)(qwb + rl1) * N_ + ((bsl ^ rl1) << 2);
  const float* bq2 = bias_h + (size_t)(qwb + rl2) * N_ + ((bsl ^ rl2) << 2);
  const float* bq3 = bias_h + (size_t)(qwb + rl3) * N_ + ((bsl ^ rl3) << 2);
  const float* bq4 = bias_h + (size_t)(qwb + rl4) * N_ + ((bsl ^ rl4) << 2);
  const float* bq5 = bias_h + (size_t)(qwb + rl5) * N_ + ((bsl ^ rl5) << 2);
  const float* bq6 = bias_h + (size_t)(qwb + rl6) * N_ + ((bsl ^ rl6) << 2);
  const float* bq7 = bias_h + (size_t)(qwb + rl7) * N_ + ((bsl ^ rl7) << 2);
  unsigned short* sB_us = reinterpret_cast<unsigned short*>(sBias[sl]);
  unsigned short* bD0 = sB_us + (size_t)(16 * wb + 0) * 256;
  unsigned short* bD1 = sB_us + (size_t)(16 * wb + 2) * 256;
  unsigned short* bD2 = sB_us + (size_t)(16 * wb + 4) * 256;
  unsigned short* bD3 = sB_us + (size_t)(16 * wb + 6) * 256;
  unsigned short* bD4 = sB_us + (size_t)(16 * wb + 8) * 256;
  unsigned short* bD5 = sB_us + (size_t)(16 * wb + 10) * 256;
  unsigned short* bD6 = sB_us + (size_t)(16 * wb + 12) * 256;
  unsigned short* bD7 = sB_us + (size_t)(16 * wb + 14) * 256;

#define STAGE_BIAS(JN)                                        \
  gload_lds16((const unsigned short*)(bq0 + (JN)), bD0);      \
  gload_lds16((const unsigned short*)(bq1 + (JN)), bD1);      \
  gload_lds16((const unsigned short*)(bq2 + (JN)), bD2);      \
  gload_lds16((const unsigned short*)(bq3 + (JN)), bD3);      \
  gload_lds16((const unsigned short*)(bq4 + (JN)), bD4);      \
  gload_lds16((const unsigned short*)(bq5 + (JN)), bD5);      \
  gload_lds16((const unsigned short*)(bq6 + (JN)), bD6);      \
  gload_lds16((const unsigned short*)(bq7 + (JN)), bD7);

// C-block from LDS bias: C[rr] = bias[q=l31][CB*4 + 8*(rr>>2)+4*hi+(rr&3)]
#define LDBIAS(DST, CB)                                                        \
  {                                                                            \
    const float* myB_ = sBias[sl] + (size_t)l31 * 128;                         \
    f32x4 t0 = *reinterpret_cast<const f32x4*>(myB_ + ((((CB) + 0 + hi) ^ l31) << 2)); \
    f32x4 t1 = *reinterpret_cast<const f32x4*>(myB_ + ((((CB) + 2 + hi) ^ l31) << 2)); \
    f32x4 t2 = *reinterpret_cast<const f32x4*>(myB_ + ((((CB) + 4 + hi) ^ l31) << 2)); \
    f32x4 t3 = *reinterpret_cast<const f32x4*>(myB_ + ((((CB) + 6 + hi) ^ l31) << 2)); \
    f32x8 u0_ = __builtin_shufflevector(t0, t1, 0, 1, 2, 3, 4, 5, 6, 7);       \
    f32x8 u1_ = __builtin_shufflevector(t2, t3, 0, 1, 2, 3, 4, 5, 6, 7);       \
    DST = __builtin_shufflevector(u0_, u1_, 0, 1, 2, 3, 4, 5, 6, 7, 8, 9, 10,  \
                                  11, 12, 13, 14, 15);                         \
  }

  const unsigned short* sKb = sK + (size_t)wb * 128 * 64;
  const unsigned short* sVb = sV + (size_t)wb * 64 * 128;

#define FRAGK(OUT, ROWB, CH)                                            \
  {                                                                     \
    int row_ = (ROWB) + l31;                                            \
    OUT = ld_frag(sKb + row_ * 64 + (((CH) ^ (row_ & 7)) * 8));         \
  }
#define FRAGV(OUT, ROWB, CH)                                            \
  {                                                                     \
    int row_ = (ROWB) + l31;                                            \
    OUT = ld_frag(sVb + row_ * 128 + (((CH) ^ (row_ & 15)) * 8));       \
  }

// pack one 32-key S block into two PV B-frags (verified r9/r10/r12)
#define PACK2(S, PLO, PHI)                                                 \
  {                                                                        \
    unsigned int w0 = cvt_pk_bf16(S[0], S[1]), w1 = cvt_pk_bf16(S[2], S[3]);     \
    unsigned int w2 = cvt_pk_bf16(S[4], S[5]), w3 = cvt_pk_bf16(S[6], S[7]);     \
    unsigned int w4 = cvt_pk_bf16(S[8], S[9]), w5 = cvt_pk_bf16(S[10], S[11]);   \
    unsigned int w6 = cvt_pk_bf16(S[12], S[13]), w7 = cvt_pk_bf16(S[14], S[15]); \
    auto rA = __builtin_amdgcn_permlane32_swap(w0, w2, false, false);      \
    auto rB = __builtin_amdgcn_permlane32_swap(w1, w3, false, false);      \
    auto rC = __builtin_amdgcn_permlane32_swap(w4, w6, false, false);      \
    auto rD = __builtin_amdgcn_permlane32_swap(w5, w7, false, false);      \
    u32x4 pw;                                                              \
    pw[0] = rA[0]; pw[1] = rB[0]; pw[2] = rA[1]; pw[3] = rB[1];            \
    PLO = __builtin_bit_cast(bf16x8, pw);                                  \
    pw[0] = rC[0]; pw[1] = rD[0]; pw[2] = rC[1]; pw[3] = rD[1];            \
    PHI = __builtin_bit_cast(bf16x8, pw);                                  \
  }

  // Q B-frags: qfK covers d = K*16 + hi*8 .. +7 for q = qwb + l31, batch wb
  bf16x8 qf0, qf1, qf2, qf3;
  {
    const unsigned short* Qg =
        qkv + (size_t)(wb * N_ + qwb + l31) * 3072 + h * 64 + hi * 8;
    qf0 = ld_frag(Qg);
    qf1 = ld_frag(Qg + 16);
    qf2 = ld_frag(Qg + 32);
    qf3 = ld_frag(Qg + 48);
  }

  f32x16 o0 = {}, o1 = {};
  float m_run = -1e30f, l_run = 0.f;

  // prologue: stage pair 0 (drained at loop-top vmcnt(0))
  STAGE_KV(0)
  STAGE_BIAS(0)

  const int NP = N_ / 128;  // 16 pairs
  for (int p = 0; p < NP; ++p) {
    asm volatile("s_waitcnt vmcnt(0) lgkmcnt(0)" ::: "memory");
    __builtin_amdgcn_s_barrier();

    // 1. bias regs for pair p (C-operands for the 4 S blocks)
    f32x16 SA0, SA1, SB0, SB1;
    LDBIAS(SA0, 0)
    LDBIAS(SA1, 8)
    LDBIAS(SB0, 16)
    LDBIAS(SB1, 24)
    asm volatile("s_waitcnt lgkmcnt(0)" ::: "memory");
    __builtin_amdgcn_sched_barrier(0);  // bias regs live before overwrite
    __builtin_amdgcn_s_barrier();       // pair partner also has its regs

    // 2. bias prefetch for pair p+1 (slice shared by wave pair; staged once)
    if (p + 1 < NP) {
      const size_t jn = (size_t)(p + 1) * 128;
      STAGE_BIAS(jn)
    }

    // 3. S^T = K Q^T + bias for both tiles of the pair
    __builtin_amdgcn_s_setprio(1);
    {
      bf16x8 kf;
      FRAGK(kf, 0, 0 + hi)  SA0 = mfma32(kf, qf0, SA0);
      FRAGK(kf, 0, 2 + hi)  SA0 = mfma32(kf, qf1, SA0);
      FRAGK(kf, 0, 4 + hi)  SA0 = mfma32(kf, qf2, SA0);
      FRAGK(kf, 0, 6 + hi)  SA0 = mfma32(kf, qf3, SA0);
      FRAGK(kf, 32, 0 + hi) SA1 = mfma32(kf, qf0, SA1);
      FRAGK(kf, 32, 2 + hi) SA1 = mfma32(kf, qf1, SA1);
      FRAGK(kf, 32, 4 + hi) SA1 = mfma32(kf, qf2, SA1);
      FRAGK(kf, 32, 6 + hi) SA1 = mfma32(kf, qf3, SA1);
      FRAGK(kf, 64, 0 + hi) SB0 = mfma32(kf, qf0, SB0);
      FRAGK(kf, 64, 2 + hi) SB0 = mfma32(kf, qf1, SB0);
      FRAGK(kf, 64, 4 + hi) SB0 = mfma32(kf, qf2, SB0);
      FRAGK(kf, 64, 6 + hi) SB0 = mfma32(kf, qf3, SB0);
      FRAGK(kf, 96, 0 + hi) SB1 = mfma32(kf, qf0, SB1);
      FRAGK(kf, 96, 2 + hi) SB1 = mfma32(kf, qf1, SB1);
      FRAGK(kf, 96, 4 + hi) SB1 = mfma32(kf, qf2, SB1);
      FRAGK(kf, 96, 6 + hi) SB1 = mfma32(kf, qf3, SB1);
    }
    __builtin_amdgcn_s_setprio(0);

    // 4. merged online softmax over 128 keys (4 parallel chains)
    float c0 = SA0[0], c1 = SA1[0], c2 = SB0[0], c3 = SB1[0];
#pragma unroll
    for (int i = 1; i < 16; ++i) {
      c0 = fmaxf(c0, SA0[i]);
      c1 = fmaxf(c1, SA1[i]);
      c2 = fmaxf(c2, SB0[i]);
      c3 = fmaxf(c3, SB1[i]);
    }
    float mx = fmaxf(fmaxf(c0, c1), fmaxf(c2, c3));
    {
      auto pr_ = __builtin_amdgcn_permlane32_swap(fasu(mx), fasu(mx), false, false);
      mx = fmaxf(uasf(pr_[0]), uasf(pr_[1]));
    }
    float mn = fmaxf(m_run, mx);
    float alpha = __expf(m_run - mn);
#pragma unroll
    for (int i = 0; i < 16; ++i) {
      SA0[i] = __expf(SA0[i] - mn);
      SA1[i] = __expf(SA1[i] - mn);
      SB0[i] = __expf(SB0[i] - mn);
      SB1[i] = __expf(SB1[i] - mn);
    }
    float r0 = 0.f, r1 = 0.f, r2 = 0.f, r3 = 0.f;
#pragma unroll
    for (int i = 0; i < 16; ++i) {
      r0 += SA0[i];
      r1 += SA1[i];
      r2 += SB0[i];
      r3 += SB1[i];
    }
    float rs = (r0 + r1) + (r2 + r3);
    {
      auto pr_ = __builtin_amdgcn_permlane32_swap(fasu(rs), fasu(rs), false, false);
      rs = uasf(pr_[0]) + uasf(pr_[1]);
    }
    l_run = l_run * alpha + rs;
    m_run = mn;
#pragma unroll
    for (int i = 0; i < 16; ++i) {
      o0[i] *= alpha;
      o1[i] *= alpha;
    }

    // 5. P -> PV B-frags in-register
    bf16x8 pA0, pA1, pA2, pA3, pB0, pB1, pB2, pB3;
    PACK2(SA0, pA0, pA1)
    PACK2(SA1, pA2, pA3)
    PACK2(SB0, pB0, pB1)
    PACK2(SB1, pB2, pB3)

    // 6. O^T += V^T P^T over the 128-key pair
    __builtin_amdgcn_s_setprio(1);
    {
      bf16x8 vf;
      FRAGV(vf, 0, 0 + hi)   o0 = mfma32(vf, pA0, o0);
      FRAGV(vf, 0, 2 + hi)   o0 = mfma32(vf, pA1, o0);
      FRAGV(vf, 0, 4 + hi)   o0 = mfma32(vf, pA2, o0);
      FRAGV(vf, 0, 6 + hi)   o0 = mfma32(vf, pA3, o0);
      FRAGV(vf, 0, 8 + hi)   o0 = mfma32(vf, pB0, o0);
      FRAGV(vf, 0, 10 + hi)  o0 = mfma32(vf, pB1, o0);
      FRAGV(vf, 0, 12 + hi)  o0 = mfma32(vf, pB2, o0);
      FRAGV(vf, 0, 14 + hi)  o0 = mfma32(vf, pB3, o0);
      FRAGV(vf, 32, 0 + hi)  o1 = mfma32(vf, pA0, o1);
      FRAGV(vf, 32, 2 + hi)  o1 = mfma32(vf, pA1, o1);
      FRAGV(vf, 32, 4 + hi)  o1 = mfma32(vf, pA2, o1);
      FRAGV(vf, 32, 6 + hi)  o1 = mfma32(vf, pA3, o1);
      FRAGV(vf, 32, 8 + hi)  o1 = mfma32(vf, pB0, o1);
      FRAGV(vf, 32, 10 + hi) o1 = mfma32(vf, pB1, o1);
      FRAGV(vf, 32, 12 + hi) o1 = mfma32(vf, pB2, o1);
      FRAGV(vf, 32, 14 + hi) o1 = mfma32(vf, pB3, o1);
    }
    __builtin_amdgcn_s_setprio(0);

    // 7. all waves done reading K/V pair p -> stage pair p+1
    asm volatile("s_waitcnt lgkmcnt(0)" ::: "memory");
    __builtin_amdgcn_s_barrier();
    if (p + 1 < NP) {
      const size_t jn = (size_t)(p + 1) * 128;
      STAGE_KV(jn)
    }
  }
#undef STAGE_KV
#undef STAGE_BIAS
#undef LDBIAS
#undef FRAGK
#undef FRAGV
#undef PACK2

  // epilogue: O[q][d] = O^T / l (batch wb)
  float inv = 1.f / l_run;
  unsigned short* orow =
      Oatt + (size_t)(wb * N_ + qwb + l31) * 1024 + h * 64 + hi * 4;
#pragma unroll
  for (int g = 0; g < 4; ++g) {
    u32x2 pk0;
    pk0[0] = cvt_pk_bf16(o0[g * 4 + 0] * inv, o0[g * 4 + 1] * inv);
    pk0[1] = cvt_pk_bf16(o0[g * 4 + 2] * inv, o0[g * 4 + 3] * inv);
    *reinterpret_cast<u32x2*>(orow + g * 8) = pk0;
    u32x2 pk1;
    pk1[0] = cvt_pk_bf16(o1[g * 4 + 0] * inv, o1[g * 4 + 1] * inv);
    pk1[1] = cvt_pk_bf16(o1[g * 4 + 2] * inv, o1[g * 4 + 3] * inv);
    *reinterpret_cast<u32x2*>(orow + 32 + g * 8) = pk1;
  }
}

extern "C" void kernel_launch(void* const* d_in, const int* in_sizes, int n_in, void* d_out,
                              int out_size, void* d_ws, size_t ws_size, hipStream_t stream) {
  const float* x = (const float*)d_in[0];
  const float* bias = (const float*)d_in[1];
  const float* g = (const float*)d_in[2];
  const float* wq = (const float*)d_in[3];
  const float* wkv = (const float*)d_in[4];
  const float* wout = (const float*)d_in[5];
  float* out = (float*)d_out;

  float* ps = (float*)d_ws;
  float* pss = ps + 16 * B_ * DIM_;
  float* meanA = pss + 16 * B_ * DIM_;
  float* sclA = meanA + B_ * DIM_;
  unsigned short* xn = (unsigned short*)(sclA + B_ * DIM_);
  unsigned short* Wqkv = xn + (size_t)4096 * 1024;
  unsigned short* WoutB = Wqkv + (size_t)3072 * 1024;
  unsigned short* qkvb = WoutB + (size_t)1024 * 1024;
  unsigned short* Vt = qkvb + (size_t)4096 * 3072;
  unsigned short* Oatt = xn;  // alias: xn dead after QKV GEMM

  ln_part<<<dim3(DIM_ / 256, B_ * 16), 256, 0, stream>>>(x, ps, pss);
  ln_fin<<<dim3((B_ * DIM_) / 256), 256, 0, stream>>>(ps, pss, g, meanA, sclA);
  ln_apply<<<dim3((B_ * N_ * DIM_) / 2048), 256, 0, stream>>>(x, meanA, sclA, xn);
  cast_bf16<<<dim3((DIM_ * DIM_) / 2048), 256, 0, stream>>>(wq, Wqkv, 0.125f);
  cast_bf16<<<dim3((2 * DIM_ * DIM_) / 2048), 256, 0, stream>>>(wkv, Wqkv + (size_t)DIM_ * DIM_,
                                                                1.0f);
  cast_bf16<<<dim3((DIM_ * DIM_) / 2048), 256, 0, stream>>>(wout, WoutB, 1.0f);
  gemm_bt<false><<<dim3(3072 / 128, 4096 / 128), 256, 0, stream>>>(xn, Wqkv, qkvb, DIM_, 3072);
  transpose_v<<<dim3(N_ / 64, B_ * HEADS_), 256, 0, stream>>>(qkvb, Vt);
  flash_attn<<<dim3(256), 512, 0, stream>>>(qkvb, bias, Vt, Oatt);
  gemm_bt<true><<<dim3(1024 / 128, 4096 / 128), 256, 0, stream>>>(Oatt, WoutB, out, DIM_, 1024);
}